// Round 14
// baseline (199.950 us; speedup 1.0000x reference)
//
#include <hip/hip_runtime.h>
#include <hip/hip_bf16.h>
#include <cstdint>

// Problem constants (N read from in_sizes at launch; C, D fixed by reference).
#define DIM 64
#define NC  1024

typedef __attribute__((ext_vector_type(8))) __bf16 bf16x8;
typedef __attribute__((ext_vector_type(8))) short short8;
typedef __attribute__((ext_vector_type(4))) float f32x4;

static __device__ __forceinline__ unsigned short f32_to_bf16_rne(float f) {
    unsigned int u = __builtin_bit_cast(unsigned int, f);
    unsigned int r = u + 0x7FFFu + ((u >> 16) & 1u);
    return (unsigned short)(r >> 16);
}

// ---------------------------------------------------------------------------
// Prep 1: normalized |coefs| weights -> wc2[c].x    (1 block, 1024 threads)
// ---------------------------------------------------------------------------
__global__ void coef_kernel(const float* __restrict__ coefs,
                            float2* __restrict__ wc2) {
    __shared__ float red[NC];
    const int c = threadIdx.x;
    const float a = fabsf(coefs[c]);
    red[c] = a;
    __syncthreads();
    for (int s = NC / 2; s > 0; s >>= 1) {
        if (c < s) red[c] += red[c + s];
        __syncthreads();
    }
    const float sum = red[0];
    const float w = (sum == 0.0f) ? a : a / sum;
    wc2[c].x = w;
}

// ---------------------------------------------------------------------------
// Prep 2: center norms -> wc2[c].y (plain f32); bf16(-2*centers) in MFMA
// B-fragment layout -> bfrag.  Grid: NC/64 blocks x 64 threads.
// ---------------------------------------------------------------------------
__global__ void center_kernel(const float* __restrict__ centers,
                              float2* __restrict__ wc2,
                              short8* __restrict__ bfrag) {
    const int c = blockIdx.x * 64 + threadIdx.x;
    const float4* row = (const float4*)(centers + (size_t)c * DIM);

    float vals[DIM];
    float c2 = 0.0f;
#pragma unroll
    for (int q = 0; q < DIM / 4; ++q) {
        float4 v = row[q];
        vals[q * 4 + 0] = v.x; vals[q * 4 + 1] = v.y;
        vals[q * 4 + 2] = v.z; vals[q * 4 + 3] = v.w;
        c2 = fmaf(v.x, v.x, c2); c2 = fmaf(v.y, v.y, c2);
        c2 = fmaf(v.z, v.z, c2); c2 = fmaf(v.w, v.w, c2);
    }
    wc2[c].y = c2;

    const int tile = c >> 4;
    const int colL = c & 15;
#pragma unroll
    for (int kb = 0; kb < 2; ++kb) {
#pragma unroll
        for (int h = 0; h < 4; ++h) {
            short8 p;
#pragma unroll
            for (int j = 0; j < 8; ++j) {
                float v = -2.0f * vals[kb * 32 + h * 8 + j];
                p[j] = (short)f32_to_bf16_rne(v);
            }
            bfrag[(tile * 2 + kb) * 64 + (h * 16 + colL)] = p;
        }
    }
}

// ---------------------------------------------------------------------------
// Main — unchanged r13 (passing, 42 us): real output producer this round.
// ---------------------------------------------------------------------------
__global__ __launch_bounds__(256, 4) void dist_kernel(
    const float* __restrict__ x,
    const float2* __restrict__ wc2,
    const bf16x8* __restrict__ bfrag,
    const float* __restrict__ madp,
    float* __restrict__ out)
{
    const int lane = threadIdx.x & 63;
    const int wave = threadIdx.x >> 6;
    const int lo = lane & 15;
    const int hi = lane >> 4;
    const int pairIdx = wave >> 1;
    const int halfC  = wave & 1;
    const int rowBase = blockIdx.x * 128 + pairIdx * 64;

    __shared__ float part[4][64];

    bf16x8 afrag[4][2];
    float x2v[4][4];

#pragma unroll
    for (int g = 0; g < 4; ++g) {
        const int row = rowBase + g * 16 + lo;
        const float* rp = x + (size_t)row * DIM + hi * 8;
        float s2 = 0.0f;
#pragma unroll
        for (int kb = 0; kb < 2; ++kb) {
            f32x4 v0 = __builtin_nontemporal_load((const f32x4*)(rp + kb * 32));
            f32x4 v1 = __builtin_nontemporal_load((const f32x4*)(rp + kb * 32 + 4));
            float vv[8] = {v0.x, v0.y, v0.z, v0.w, v1.x, v1.y, v1.z, v1.w};
            short8 p;
#pragma unroll
            for (int j = 0; j < 8; ++j) {
                s2 = fmaf(vv[j], vv[j], s2);
                p[j] = (short)f32_to_bf16_rne(vv[j]);
            }
            afrag[g][kb] = __builtin_bit_cast(bf16x8, p);
        }
        s2 += __shfl_xor(s2, 16, 64);
        s2 += __shfl_xor(s2, 32, 64);
#pragma unroll
        for (int b = 0; b < 4; ++b)
            x2v[g][b] = __shfl(s2, hi * 4 + b, 64);
    }

    float sum[4][4];
#pragma unroll
    for (int g = 0; g < 4; ++g)
#pragma unroll
        for (int b = 0; b < 4; ++b) sum[g][b] = 0.0f;

    const int tbase = halfC * 32;
    const bf16x8* bp = bfrag + lane;
    const float2* wp = wc2 + lo;

    bf16x8 pb0[2], pb1[2];
    float2 pwc[2];
#pragma unroll
    for (int s = 0; s < 2; ++s) {
        const int t = tbase + s;
        pb0[s] = bp[t * 128];
        pb1[s] = bp[t * 128 + 64];
        pwc[s] = wp[t * 16];
    }

#pragma unroll 1
    for (int i = 0; i < 32; i += 2) {
        const float2 wcA = pwc[0], wcB = pwc[1];
        const bf16x8 a00 = pb0[0], a01 = pb1[0];
        const bf16x8 a10 = pb0[1], a11 = pb1[1];

        {
            const int n0 = i + 2, n1 = i + 3;
            const int t0 = tbase + ((n0 < 32) ? n0 : 0);
            const int t1 = tbase + ((n1 < 32) ? n1 : 0);
            pb0[0] = bp[t0 * 128]; pb1[0] = bp[t0 * 128 + 64]; pwc[0] = wp[t0 * 16];
            pb0[1] = bp[t1 * 128]; pb1[1] = bp[t1 * 128 + 64]; pwc[1] = wp[t1 * 16];
        }

        f32x4 acc0[4], acc1[4];
#pragma unroll
        for (int g = 0; g < 4; ++g)
#pragma unroll
            for (int b = 0; b < 4; ++b) {
                acc0[g][b] = x2v[g][b] + wcA.y;
                acc1[g][b] = x2v[g][b] + wcB.y;
            }

#pragma unroll
        for (int g = 0; g < 4; ++g)
            acc0[g] = __builtin_amdgcn_mfma_f32_16x16x32_bf16(afrag[g][0], a00, acc0[g], 0, 0, 0);
#pragma unroll
        for (int g = 0; g < 4; ++g)
            acc1[g] = __builtin_amdgcn_mfma_f32_16x16x32_bf16(afrag[g][0], a10, acc1[g], 0, 0, 0);
#pragma unroll
        for (int g = 0; g < 4; ++g)
            acc0[g] = __builtin_amdgcn_mfma_f32_16x16x32_bf16(afrag[g][1], a01, acc0[g], 0, 0, 0);
#pragma unroll
        for (int g = 0; g < 4; ++g)
            acc1[g] = __builtin_amdgcn_mfma_f32_16x16x32_bf16(afrag[g][1], a11, acc1[g], 0, 0, 0);

#pragma unroll
        for (int g = 0; g < 4; ++g)
#pragma unroll
            for (int b = 0; b < 4; ++b) {
                float d = __builtin_amdgcn_sqrtf(fabsf(acc0[g][b]));
                sum[g][b] = fmaf(wcA.x, d, sum[g][b]);
            }
#pragma unroll
        for (int g = 0; g < 4; ++g)
#pragma unroll
            for (int b = 0; b < 4; ++b) {
                float d = __builtin_amdgcn_sqrtf(fabsf(acc1[g][b]));
                sum[g][b] = fmaf(wcB.x, d, sum[g][b]);
            }
    }

#pragma unroll
    for (int g = 0; g < 4; ++g) {
#pragma unroll
        for (int b = 0; b < 4; ++b) {
            float v = sum[g][b];
            v += __shfl_xor(v, 1, 64);
            v += __shfl_xor(v, 2, 64);
            v += __shfl_xor(v, 4, 64);
            v += __shfl_xor(v, 8, 64);
            if (lo == 0) part[wave][g * 16 + hi * 4 + b] = v;
        }
    }
    __syncthreads();

    const int tid = threadIdx.x;
    if (tid < 128) {
        const int p = tid >> 6;
        const int r = tid & 63;
        const float s = part[2 * p][r] + part[2 * p + 1][r];
        __builtin_nontemporal_store(madp[0] - s, &out[blockIdx.x * 128 + p * 64 + r]);
    }
}

// ---------------------------------------------------------------------------
// DIAGNOSTIC PROBE (round 14): identical prologue + per-tile compute, but
// ZERO in-loop memory loads — B operands come from registers (afrag), the
// acc-init scalar varies by (t,rep) to defeat loop-invariant hoisting, and
// the sqrt+fma epilogue feeds a live scratch write. Repeated R=8 so its
// replays dominate the top-5 rocprof table. Per-pass time = dur_us / 8.
//   per-pass <= 12 us  -> B/wc global-load path is the ~30 us stall
//   per-pass >= 35 us  -> memory innocent; compute structure is the wall
// ---------------------------------------------------------------------------
__global__ __launch_bounds__(256, 4) void probe_nob(
    const float* __restrict__ x,
    float* __restrict__ scratch)
{
    const int lane = threadIdx.x & 63;
    const int wave = threadIdx.x >> 6;
    const int lo = lane & 15;
    const int hi = lane >> 4;
    const int pairIdx = wave >> 1;
    const int rowBase = blockIdx.x * 128 + pairIdx * 64;

    __shared__ float part[4][64];

    bf16x8 afrag[4][2];
    float x2v[4][4];

    // Prologue: identical shape to dist_kernel.
#pragma unroll
    for (int g = 0; g < 4; ++g) {
        const int row = rowBase + g * 16 + lo;
        const float* rp = x + (size_t)row * DIM + hi * 8;
        float s2 = 0.0f;
#pragma unroll
        for (int kb = 0; kb < 2; ++kb) {
            f32x4 v0 = *(const f32x4*)(rp + kb * 32);
            f32x4 v1 = *(const f32x4*)(rp + kb * 32 + 4);
            float vv[8] = {v0.x, v0.y, v0.z, v0.w, v1.x, v1.y, v1.z, v1.w};
            short8 p;
#pragma unroll
            for (int j = 0; j < 8; ++j) {
                s2 = fmaf(vv[j], vv[j], s2);
                p[j] = (short)f32_to_bf16_rne(vv[j]);
            }
            afrag[g][kb] = __builtin_bit_cast(bf16x8, p);
        }
        s2 += __shfl_xor(s2, 16, 64);
        s2 += __shfl_xor(s2, 32, 64);
#pragma unroll
        for (int b = 0; b < 4; ++b)
            x2v[g][b] = __shfl(s2, hi * 4 + b, 64);
    }

    float sum[4][4];
#pragma unroll
    for (int g = 0; g < 4; ++g)
#pragma unroll
        for (int b = 0; b < 4; ++b) sum[g][b] = 0.0f;

#pragma unroll 1
    for (int rep = 0; rep < 8; ++rep) {
#pragma unroll 1
        for (int t = 0; t < 32; ++t) {
            const float cinit = (float)(t + rep);   // defeats hoisting

            f32x4 acc0[4];
#pragma unroll
            for (int g = 0; g < 4; ++g)
#pragma unroll
                for (int b = 0; b < 4; ++b)
                    acc0[g][b] = x2v[g][b] + cinit;

#pragma unroll
            for (int g = 0; g < 4; ++g)
                acc0[g] = __builtin_amdgcn_mfma_f32_16x16x32_bf16(
                    afrag[g][0], afrag[(g + 1) & 3][0], acc0[g], 0, 0, 0);
#pragma unroll
            for (int g = 0; g < 4; ++g)
                acc0[g] = __builtin_amdgcn_mfma_f32_16x16x32_bf16(
                    afrag[g][1], afrag[(g + 2) & 3][1], acc0[g], 0, 0, 0);

#pragma unroll
            for (int g = 0; g < 4; ++g)
#pragma unroll
                for (int b = 0; b < 4; ++b) {
                    float d = __builtin_amdgcn_sqrtf(fabsf(acc0[g][b]));
                    sum[g][b] = fmaf(0.125f, d, sum[g][b]);
                }
        }
    }

#pragma unroll
    for (int g = 0; g < 4; ++g) {
#pragma unroll
        for (int b = 0; b < 4; ++b) {
            float v = sum[g][b];
            v += __shfl_xor(v, 1, 64);
            v += __shfl_xor(v, 2, 64);
            v += __shfl_xor(v, 4, 64);
            v += __shfl_xor(v, 8, 64);
            if (lo == 0) part[wave][g * 16 + hi * 4 + b] = v;
        }
    }
    __syncthreads();

    const int tid = threadIdx.x;
    if (tid < 128) {
        const int p = tid >> 6;
        const int r = tid & 63;
        scratch[blockIdx.x * 128 + p * 64 + r] =
            part[2 * p][r & 63] + part[2 * p + 1][r & 63];
    }
}

extern "C" void kernel_launch(void* const* d_in, const int* in_sizes, int n_in,
                              void* d_out, int out_size, void* d_ws, size_t ws_size,
                              hipStream_t stream) {
    const float* x       = (const float*)d_in[0];
    const float* centers = (const float*)d_in[1];
    const float* coefs   = (const float*)d_in[2];
    const float* mad     = (const float*)d_in[3];
    float* out = (float*)d_out;

    float2* wc2   = (float2*)d_ws;
    short8* bfrag = (short8*)((char*)d_ws + NC * sizeof(float2));
    float* scratch = (float*)((char*)d_ws + NC * sizeof(float2)
                              + (size_t)NC * DIM * sizeof(short));

    const int N = in_sizes[0] / DIM;

    coef_kernel<<<1, NC, 0, stream>>>(coefs, wc2);
    center_kernel<<<NC / 64, 64, 0, stream>>>(centers, wc2, bfrag);
    dist_kernel<<<N / 128, 256, 0, stream>>>(x, wc2, (const bf16x8*)bfrag, mad, out);
    probe_nob<<<N / 128, 256, 0, stream>>>(x, scratch);
}

// Round 15
// 49.085 us; speedup vs baseline: 4.0735x; 4.0735x over previous
//
#include <hip/hip_runtime.h>
#include <hip/hip_bf16.h>
#include <cstdint>

// Problem constants (N read from in_sizes at launch; C, D fixed by reference).
#define DIM 64
#define NC  1024
#define NCHUNK 8        // 8 chunks x 4 tiles per half

typedef __attribute__((ext_vector_type(8))) __bf16 bf16x8;
typedef __attribute__((ext_vector_type(8))) short short8;
typedef __attribute__((ext_vector_type(4))) float f32x4;
typedef __attribute__((ext_vector_type(4))) unsigned int uint4v;

static __device__ __forceinline__ unsigned short f32_to_bf16_rne(float f) {
    unsigned int u = __builtin_bit_cast(unsigned int, f);
    unsigned int r = u + 0x7FFFu + ((u >> 16) & 1u);
    return (unsigned short)(r >> 16);
}
static __device__ __forceinline__ float bf16_bits_to_f32(unsigned short h) {
    return __builtin_bit_cast(float, (unsigned int)h << 16);
}

// ---------------------------------------------------------------------------
// Prep 1: normalized |coefs| weights -> wc2[c].x    (1 block, 1024 threads)
// ---------------------------------------------------------------------------
__global__ void coef_kernel(const float* __restrict__ coefs,
                            float2* __restrict__ wc2) {
    __shared__ float red[NC];
    const int c = threadIdx.x;
    const float a = fabsf(coefs[c]);
    red[c] = a;
    __syncthreads();
    for (int s = NC / 2; s > 0; s >>= 1) {
        if (c < s) red[c] += red[c + s];
        __syncthreads();
    }
    const float sum = red[0];
    const float w = (sum == 0.0f) ? a : a / sum;
    wc2[c].x = w;
}

// ---------------------------------------------------------------------------
// Prep 2 (r4-proven): per-center c2 as bf16 (hi, residual) pair packed in
// wc2[c].y; bf16(-2*centers) in MFMA B-fragment layout -> bfrag.
// B-fragment layout for mfma_f32_16x16x32_bf16:
//   lane supplies B[k][col] with col = lane&15, k = (lane>>4)*8 + j.
//   Stored as bfrag[(tile*2 + kb)*64 + lane] : short8 (16B per lane).
// ---------------------------------------------------------------------------
__global__ void center_kernel(const float* __restrict__ centers,
                              float2* __restrict__ wc2,
                              short8* __restrict__ bfrag) {
    const int c = blockIdx.x * 64 + threadIdx.x;
    const float4* row = (const float4*)(centers + (size_t)c * DIM);

    float vals[DIM];
    float c2 = 0.0f;
#pragma unroll
    for (int q = 0; q < DIM / 4; ++q) {
        float4 v = row[q];
        vals[q * 4 + 0] = v.x; vals[q * 4 + 1] = v.y;
        vals[q * 4 + 2] = v.z; vals[q * 4 + 3] = v.w;
        c2 = fmaf(v.x, v.x, c2); c2 = fmaf(v.y, v.y, c2);
        c2 = fmaf(v.z, v.z, c2); c2 = fmaf(v.w, v.w, c2);
    }
    // hi + residual bf16 split: k=0 slot carries hi, k=1 slot carries lo.
    const unsigned short hi = f32_to_bf16_rne(c2);
    const unsigned short lo = f32_to_bf16_rne(c2 - bf16_bits_to_f32(hi));
    const unsigned int packed = (unsigned int)hi | ((unsigned int)lo << 16);
    wc2[c].y = __builtin_bit_cast(float, packed);

    const int tile = c >> 4;
    const int colL = c & 15;
#pragma unroll
    for (int kb = 0; kb < 2; ++kb) {
#pragma unroll
        for (int h = 0; h < 4; ++h) {
            short8 p;
#pragma unroll
            for (int j = 0; j < 8; ++j) {
                float v = -2.0f * vals[kb * 32 + h * 8 + j];
                p[j] = (short)f32_to_bf16_rne(v);
            }
            bfrag[(tile * 2 + kb) * 64 + (h * 16 + colL)] = p;
        }
    }
}

// ---------------------------------------------------------------------------
// Main (round 15). Measured decomposition (r14 probe): compute=22.6us,
// in-loop global loads=+19.4us of unhidden stall. Fixes:
//  (1) B + wc move to LDS. Reg-staged double-buffered 16KB chunks (4 tiles
//      per half): issue chunk c+1's global loads at the TOP of chunk c's
//      ~800-cyc compute, ds_write after (T14 issue-early/write-late), ONE
//      barrier per chunk. NOT global_load_lds (r8: bypasses L2 reuse).
//      wc2 (8KB) staged once in the prologue.
//  (2) acc-init back on the MFMA pipe (r4's afones x bc2 trick, hi+residual
//      packing) — probe shows ~94% issue saturation, so deleting 16 VALU
//      adds/tile is direct win; chain depth proven irrelevant (r10/r11).
// Structure: block = 256 thr = 4 waves; pair = wave>>1 owns 64 rows;
// halfC = wave&1 owns a 512-center half. launch_bounds(256,4) = r4-proven
// allocator budget; LDS 41KB caps residency at 3 blocks/CU (= observed).
// Outer chunk loop pinned rolled (r6 spill lesson).
// ---------------------------------------------------------------------------
__global__ __launch_bounds__(256, 4) void dist_kernel(
    const float* __restrict__ x,
    const float2* __restrict__ wc2,
    const char* __restrict__ bfragB,   // byte view of bfrag
    const float* __restrict__ madp,
    float* __restrict__ out)
{
    const int tid  = threadIdx.x;
    const int lane = tid & 63;
    const int wave = tid >> 6;
    const int lo = lane & 15;
    const int hi = lane >> 4;
    const int pairIdx = wave >> 1;
    const int halfC  = wave & 1;
    const int rowBase = blockIdx.x * 128 + pairIdx * 64;

    __shared__ char lbuf[2][16384];    // double-buffered chunk [half0 8K | half1 8K]
    __shared__ float2 wcl[NC];         // 8KB: (w, packed-c2) per center
    __shared__ float part[4][64];

    // ---- Issue chunk-0 staging loads FIRST (fly under the whole prologue).
    f32x4 st0[4];
#pragma unroll
    for (int r = 0; r < 4; ++r) {
        const int local = r * 4096 + tid * 16;
        const char* src = (local < 8192)
            ? (bfragB + local)                        // half0 tiles 0..3
            : (bfragB + 65536 + (local - 8192));      // half1 tiles 32..35
        st0[r] = *(const f32x4*)src;
    }
    // wc2 -> LDS (8KB, one-time coop copy).
    {
        const f32x4* wsrc = (const f32x4*)wc2;
        f32x4* wdst = (f32x4*)wcl;
        wdst[tid * 2]     = wsrc[tid * 2];
        wdst[tid * 2 + 1] = wsrc[tid * 2 + 1];
    }

    // ---- Prologue: load A rows, bf16 fragments, x2 per row (r4 layout).
    bf16x8 afrag[4][2];
    f32x4 x2c[4];
#pragma unroll
    for (int g = 0; g < 4; ++g) {
        const int row = rowBase + g * 16 + lo;
        const float* rp = x + (size_t)row * DIM + hi * 8;
        float s2 = 0.0f;
#pragma unroll
        for (int kb = 0; kb < 2; ++kb) {
            f32x4 v0 = *(const f32x4*)(rp + kb * 32);
            f32x4 v1 = *(const f32x4*)(rp + kb * 32 + 4);
            float vv[8] = {v0.x, v0.y, v0.z, v0.w, v1.x, v1.y, v1.z, v1.w};
            short8 p;
#pragma unroll
            for (int j = 0; j < 8; ++j) {
                s2 = fmaf(vv[j], vv[j], s2);
                p[j] = (short)f32_to_bf16_rne(vv[j]);
            }
            afrag[g][kb] = __builtin_bit_cast(bf16x8, p);
        }
        s2 += __shfl_xor(s2, 16, 64);
        s2 += __shfl_xor(s2, 32, 64);
#pragma unroll
        for (int b = 0; b < 4; ++b)
            x2c[g][b] = __shfl(s2, hi * 4 + b, 64);
    }

    // Constant A fragment [1,1,0,...,0] (k=0,1 live in the hi==0 lane group).
    const unsigned int ao = (hi == 0) ? 0x3F803F80u : 0u;
    const bf16x8 afones = __builtin_bit_cast(bf16x8, (uint4v){ao, 0u, 0u, 0u});

    float sum[4][4];
#pragma unroll
    for (int g = 0; g < 4; ++g)
#pragma unroll
        for (int b = 0; b < 4; ++b) sum[g][b] = 0.0f;

    // ---- Publish chunk 0 (vmcnt waited here, after the prologue covered it).
#pragma unroll
    for (int r = 0; r < 4; ++r)
        *(f32x4*)&lbuf[0][r * 4096 + tid * 16] = st0[r];
    __syncthreads();

    const int myLds = halfC * 8192;
    int cb = 0;

#pragma unroll 1   // MUST stay rolled (round 6: full unroll -> spill)
    for (int c = 0; c < NCHUNK; ++c) {
        // (1) Issue chunk c+1 global loads — consumed only at the ds_write
        // below, ~800 cyc of compute later.
        f32x4 stg[4];
        if (c + 1 < NCHUNK) {
#pragma unroll
            for (int r = 0; r < 4; ++r) {
                const int local = r * 4096 + tid * 16;
                const char* src = (local < 8192)
                    ? (bfragB + (size_t)(c + 1) * 8192 + local)
                    : (bfragB + 65536 + (size_t)(c + 1) * 8192 + (local - 8192));
                stg[r] = *(const f32x4*)src;
            }
        }

        // (2) Compute this chunk's 4 tiles from LDS.
#pragma unroll
        for (int lt = 0; lt < 4; ++lt) {
            const int ct = halfC * 32 + c * 4 + lt;       // global tile id
            const float2 wc = wcl[ct * 16 + lo];
            const float w = wc.x;
            const unsigned int packed = __builtin_bit_cast(unsigned int, wc.y);
            const bf16x8 bc2 = __builtin_bit_cast(bf16x8,
                (uint4v){(hi == 0) ? packed : 0u, 0u, 0u, 0u});

            const char* tp = &lbuf[cb][myLds + lt * 2048 + lane * 16];
            const bf16x8 b0 = *(const bf16x8*)tp;
            const bf16x8 b1 = *(const bf16x8*)(tp + 1024);

#pragma unroll
            for (int g = 0; g < 4; ++g) {
                f32x4 acc;
                acc = __builtin_amdgcn_mfma_f32_16x16x32_bf16(afones, bc2, x2c[g], 0, 0, 0);
                acc = __builtin_amdgcn_mfma_f32_16x16x32_bf16(afrag[g][0], b0, acc, 0, 0, 0);
                acc = __builtin_amdgcn_mfma_f32_16x16x32_bf16(afrag[g][1], b1, acc, 0, 0, 0);
#pragma unroll
                for (int b = 0; b < 4; ++b) {
                    float d = __builtin_amdgcn_sqrtf(fabsf(acc[b]));
                    sum[g][b] = fmaf(w, d, sum[g][b]);
                }
            }
        }

        // (3) Write staged chunk to the other buffer; publish.
        if (c + 1 < NCHUNK) {
#pragma unroll
            for (int r = 0; r < 4; ++r)
                *(f32x4*)&lbuf[cb ^ 1][r * 4096 + tid * 16] = stg[r];
        }
        __syncthreads();
        cb ^= 1;
    }

    // Reduce over the 16 col-lanes of this wave's half, park in LDS.
#pragma unroll
    for (int g = 0; g < 4; ++g) {
#pragma unroll
        for (int b = 0; b < 4; ++b) {
            float v = sum[g][b];
            v += __shfl_xor(v, 1, 64);
            v += __shfl_xor(v, 2, 64);
            v += __shfl_xor(v, 4, 64);
            v += __shfl_xor(v, 8, 64);
            if (lo == 0) part[wave][g * 16 + hi * 4 + b] = v;
        }
    }
    __syncthreads();

    // Combine the two center-halves and write 128 rows.
    if (tid < 128) {
        const int p = tid >> 6;
        const int r = tid & 63;
        const float s = part[2 * p][r] + part[2 * p + 1][r];
        out[blockIdx.x * 128 + p * 64 + r] = madp[0] - s;
    }
}

extern "C" void kernel_launch(void* const* d_in, const int* in_sizes, int n_in,
                              void* d_out, int out_size, void* d_ws, size_t ws_size,
                              hipStream_t stream) {
    const float* x       = (const float*)d_in[0];
    const float* centers = (const float*)d_in[1];
    const float* coefs   = (const float*)d_in[2];
    const float* mad     = (const float*)d_in[3];
    float* out = (float*)d_out;

    float2* wc2   = (float2*)d_ws;
    short8* bfrag = (short8*)((char*)d_ws + NC * sizeof(float2));

    const int N = in_sizes[0] / DIM;

    coef_kernel<<<1, NC, 0, stream>>>(coefs, wc2);
    center_kernel<<<NC / 64, 64, 0, stream>>>(centers, wc2, bfrag);
    dist_kernel<<<N / 128, 256, 0, stream>>>(x, wc2, (const char*)bfrag, mad, out);
}